// Round 7
// baseline (257.695 us; speedup 1.0000x reference)
//
#include <hip/hip_runtime.h>

// Problem: B=2, S=2048, D=1024, H=16, DK=64. fp32 in/out, bf16 MFMA inside.
constexpr float kScale = 0.125f;            // 1/sqrt(64)
constexpr float kLog2e = 1.44269504088896f; // softmax runs in exp2 domain

typedef __attribute__((ext_vector_type(8))) short bf16x8;
typedef __attribute__((ext_vector_type(4))) float f32x4;

static __device__ __forceinline__ ushort f2bf(float f) {
  uint u = __float_as_uint(f);
  return (ushort)((u + 0x7fffu + ((u >> 16) & 1u)) >> 16);  // RNE
}

static __device__ __forceinline__ float exp2_fast(float x) {
  float r;
  asm("v_exp_f32 %0, %1" : "=v"(r) : "v"(x));
  return r;
}

static __device__ __forceinline__ uint cvt_pk_bf16(float lo, float hi) {
  uint r;
  asm("v_cvt_pk_bf16_f32 %0, %1, %2" : "=v"(r) : "v"(lo), "v"(hi));
  return r;
}

#define GLD_LDS16(g, l)                                        \
  __builtin_amdgcn_global_load_lds(                            \
      (const __attribute__((address_space(1))) void*)(g),      \
      (__attribute__((address_space(3))) void*)(l), 16, 0, 0)

// ---------------------------------------------------------------------------
// fp32 -> bf16 pack, 8 elems/thread
// ---------------------------------------------------------------------------
__global__ __launch_bounds__(256) void cvt_f32_bf16(
    const float* __restrict__ in, ushort* __restrict__ out, int n8) {
  int i = blockIdx.x * 256 + threadIdx.x;
  if (i >= n8) return;
  float4 a = ((const float4*)in)[2 * i];
  float4 b = ((const float4*)in)[2 * i + 1];
  union { ushort u[8]; int4 v; } r;
  r.u[0] = f2bf(a.x); r.u[1] = f2bf(a.y); r.u[2] = f2bf(a.z); r.u[3] = f2bf(a.w);
  r.u[4] = f2bf(b.x); r.u[5] = f2bf(b.y); r.u[6] = f2bf(b.z); r.u[7] = f2bf(b.w);
  ((int4*)out)[i] = r.v;
}

// ---------------------------------------------------------------------------
// Per-64x64-tile mask classification: 1=all-nonzero, 2=all-zero, 0=mixed
// ---------------------------------------------------------------------------
__global__ __launch_bounds__(256) void mask_flags(
    const int* __restrict__ mask, int* __restrict__ flags) {
  const int bid = blockIdx.x;            // b*1024 + qt*32 + kt
  const int b = bid >> 10, qt = (bid >> 5) & 31, kt = bid & 31;
  const int t = threadIdx.x;
  bool nz = true, z = true;
#pragma unroll
  for (int i = 0; i < 4; ++i) {
    const int f = t + i * 256;           // 0..1023
    const int row = f >> 4, c4 = (f & 15) * 4;
    const int4 v = *(const int4*)&mask[(size_t)(b * 2048 + qt * 64 + row) * 2048 + kt * 64 + c4];
    nz = nz && v.x && v.y && v.z && v.w;
    z = z && !v.x && !v.y && !v.z && !v.w;
  }
  __shared__ int snz[4], sz[4];
  const int wnz = __all(nz), wz = __all(z);
  if ((t & 63) == 0) { snz[t >> 6] = wnz; sz[t >> 6] = wz; }
  __syncthreads();
  if (t == 0) {
    const int a = snz[0] & snz[1] & snz[2] & snz[3];
    const int c = sz[0] & sz[1] & sz[2] & sz[3];
    flags[bid] = a ? 1 : (c ? 2 : 0);
  }
}

// ---------------------------------------------------------------------------
// bf16 GEMM (m97 structure): C = A @ W^T (+bias). 128x128 tile, 4 waves, BK=32,
// global_load_lds staging, swizzled LDS, 16x16x32 MFMA.
// MODE 1: bias + scatter: Q (pre-scaled by kScale*log2e) / K -> [bh][s][dk];
//         V -> [bh][dk][s] (transposed here).  MODE 0: bias + fp32 out.
// ---------------------------------------------------------------------------
template <int MODE>
__global__ __launch_bounds__(256) void gemm_bt(
    const ushort* __restrict__ A, const ushort* __restrict__ W,
    const float* __restrict__ bias, ushort* __restrict__ q_ws,
    ushort* __restrict__ k_ws, ushort* __restrict__ v_ws,
    float* __restrict__ outf) {
  __shared__ __align__(16) ushort As[128 * 32];
  __shared__ __align__(16) ushort Bs[128 * 32];
  const int tid = threadIdx.x;
  const int m0 = blockIdx.x * 128, n0 = blockIdx.y * 128;
  const int w = tid >> 6, lane = tid & 63;
  const int wr = w >> 1, wc = w & 1;
  const int lrow = lane & 15, kg = lane >> 4;

  f32x4 acc[4][4] = {};

  for (int k0 = 0; k0 < 1024; k0 += 32) {
    __syncthreads();
#pragma unroll
    for (int i = 0; i < 4; ++i) {
      const int f = tid + i * 256;
      const int fl = f & 511;
      const int row = fl >> 2, kgd = fl & 3;
      const int kgs = kgd ^ ((row >> 1) & 3);
      const ushort* gsrc = (f < 512)
          ? &A[(size_t)(m0 + row) * 1024 + k0 + kgs * 8]
          : &W[(size_t)(n0 + row) * 1024 + k0 + kgs * 8];
      ushort* ldst = (f < 512) ? &As[fl * 8] : &Bs[fl * 8];
      GLD_LDS16(gsrc, ldst);
    }
    __syncthreads();

    bf16x8 av[4], bv[4];
#pragma unroll
    for (int m = 0; m < 4; ++m) {
      const int row = wr * 64 + m * 16 + lrow;
      av[m] = *(const bf16x8*)&As[row * 32 + (kg ^ ((row >> 1) & 3)) * 8];
    }
#pragma unroll
    for (int n = 0; n < 4; ++n) {
      const int row = wc * 64 + n * 16 + lrow;
      bv[n] = *(const bf16x8*)&Bs[row * 32 + (kg ^ ((row >> 1) & 3)) * 8];
    }
    __builtin_amdgcn_s_setprio(1);
#pragma unroll
    for (int m = 0; m < 4; ++m)
#pragma unroll
      for (int n = 0; n < 4; ++n)
        acc[m][n] = __builtin_amdgcn_mfma_f32_16x16x32_bf16(av[m], bv[n], acc[m][n], 0, 0, 0);
    __builtin_amdgcn_s_setprio(0);
  }

  // C/D: col = lane&15, row = (lane>>4)*4 + j
  if (MODE == 1) {
#pragma unroll
    for (int n = 0; n < 4; ++n) {
      const int col = n0 + wc * 64 + n * 16 + lrow;
      const float bj = bias[col];
      const int sel = col >> 10, h = (col >> 6) & 15, dk = col & 63;
      if (sel == 2) {
        // V: [bh][dk][s], j walks s contiguously -> uint2 stores
#pragma unroll
        for (int m = 0; m < 4; ++m) {
          const int mrow0 = m0 + wr * 64 + m * 16 + kg * 4;
          const int b = mrow0 >> 11, s = mrow0 & 2047;
          union { ushort u[4]; uint2 v; } pk;
#pragma unroll
          for (int j = 0; j < 4; ++j) pk.u[j] = f2bf(acc[m][n][j] + bj);
          *(uint2*)&v_ws[((size_t)(b * 16 + h) * 64 + dk) * 2048 + s] = pk.v;
        }
      } else {
        // Q pre-scaled by kScale*log2e so flash softmax runs in exp2 domain
        const float scl = (sel == 0) ? kScale * kLog2e : 1.f;
        ushort* dst = sel == 0 ? q_ws : k_ws;
#pragma unroll
        for (int m = 0; m < 4; ++m)
#pragma unroll
          for (int j = 0; j < 4; ++j) {
            const int mrow = m0 + wr * 64 + m * 16 + kg * 4 + j;
            const int b = mrow >> 11, s = mrow & 2047;
            dst[((size_t)(b * 16 + h) * 2048 + s) * 64 + dk] =
                f2bf((acc[m][n][j] + bj) * scl);
          }
      }
    }
  } else {
#pragma unroll
    for (int n = 0; n < 4; ++n) {
      const int col = n0 + wc * 64 + n * 16 + lrow;
      const float bj = bias[col];
#pragma unroll
      for (int m = 0; m < 4; ++m)
#pragma unroll
        for (int j = 0; j < 4; ++j) {
          const int mrow = m0 + wr * 64 + m * 16 + kg * 4 + j;
          outf[(size_t)mrow * 1024 + col] = acc[m][n][j] + bj;
        }
    }
  }
}

// ---------------------------------------------------------------------------
// Flash attention v3: swapped QK^T (per-lane softmax in exp2 domain), K/V LDS
// double-buffered via global_load_lds (pre-swizzled source), defer-max,
// cvt_pk P-pack. Block = 64 q-rows of one (b,h); 4 waves x 16 q-rows.
// ---------------------------------------------------------------------------
__global__ __launch_bounds__(256) void flash_attn(
    const ushort* __restrict__ Q, const ushort* __restrict__ K,
    const ushort* __restrict__ Vt, const int* __restrict__ mask,
    const int* __restrict__ flags, ushort* __restrict__ AO) {
  __shared__ __align__(16) ushort Ks[2][64 * 64];  // [k-row][dk], swizzled
  __shared__ __align__(16) ushort Vs[2][64 * 64];  // [dk-row][k], swizzled
  __shared__ __align__(16) ushort Ps[4][16 * 64];  // per-wave P, swizzled

  const int id = blockIdx.x;
  const int xcd = id & 7, sub = id >> 3;
  const int bh = xcd * 4 + (sub >> 5), qt = sub & 31;
  const int b = bh >> 4, h = bh & 15;
  const int q0 = qt * 64;
  const int tid = threadIdx.x, w = tid >> 6, lane = tid & 63;
  const int lrow = lane & 15, kg = lane >> 4;
  const int t7 = lrow & 7;
  const size_t kbase = (size_t)bh * 2048 * 64;  // Q,K: [bh][2048][64]
  const size_t vbase = (size_t)bh * 64 * 2048;  // Vt:  [bh][64][2048]
  const int qrow = q0 + w * 16 + lrow;          // this lane's q-row

  // staging: LDS byte addr = wave-base + lane*16 (linear), as required
  const int srow = tid >> 3, sg = tid & 7;

  bf16x8 bq[2];
#pragma unroll
  for (int s = 0; s < 2; ++s)
    bq[s] = *(const bf16x8*)&Q[kbase + (size_t)qrow * 64 + s * 32 + kg * 8];

  float mi = -1e30f, li = 0.f;
  f32x4 oacc[4] = {};  // [n][j]: O[q=kg*4+j][dk=n*16+lrow]
  ushort* pl = &Ps[w][0];
  const int* fbase = flags + (b * 32 + qt) * 32;

  auto STAGE = [&](int buf, int kt) {
    const int k0 = kt * 64;
#pragma unroll
    for (int i = 0; i < 2; ++i) {
      const int r = srow + i * 32;
      GLD_LDS16(&K[kbase + (size_t)(k0 + r) * 64 + (sg ^ (r & 7)) * 8],
                &Ks[buf][r * 64 + sg * 8]);
      GLD_LDS16(&Vt[vbase + (size_t)r * 2048 + k0 + (sg ^ (r & 7)) * 8],
                &Vs[buf][r * 64 + sg * 8]);
    }
  };

  STAGE(0, 0);
  __syncthreads();  // drains vmcnt(0): tile 0 ready

  for (int kt = 0; kt < 32; ++kt) {
    const int cur = kt & 1;
    if (kt < 31) STAGE(cur ^ 1, kt + 1);  // async, lands before next barrier
    const int flag = fbase[kt];
    const int k0 = kt * 64;

    // S^T = K @ Q^T : sacc[m][j] = S[k0 + m*16 + kg*4 + j][q = qrow] (x log2e)
    f32x4 sacc[4] = {};
    __builtin_amdgcn_s_setprio(1);
#pragma unroll
    for (int s = 0; s < 2; ++s)
#pragma unroll
      for (int m = 0; m < 4; ++m) {
        const bf16x8 ak = *(const bf16x8*)
            &Ks[cur][(m * 16 + lrow) * 64 + ((s * 4 + kg) ^ t7) * 8];
        sacc[m] = __builtin_amdgcn_mfma_f32_16x16x32_bf16(ak, bq[s], sacc[m], 0, 0, 0);
      }
    __builtin_amdgcn_s_setprio(0);

    float sv[16];
#pragma unroll
    for (int m = 0; m < 4; ++m)
#pragma unroll
      for (int j = 0; j < 4; ++j) sv[m * 4 + j] = sacc[m][j];

    if (flag == 2) {
#pragma unroll
      for (int i = 0; i < 16; ++i) sv[i] = -1e9f;
    } else if (flag == 0) {
      const int* mrow = &mask[(size_t)(b * 2048 + qrow) * 2048 + k0];
#pragma unroll
      for (int m = 0; m < 4; ++m)
#pragma unroll
        for (int j = 0; j < 4; ++j)
          if (mrow[m * 16 + kg * 4 + j] == 0) sv[m * 4 + j] = -1e9f;
    }

    // per-lane row max: max3-fusable tree, then 2-step cross-kg reduce
    float t0 = fmaxf(fmaxf(fmaxf(sv[0], sv[1]), sv[2]), sv[3]);
    float t1 = fmaxf(fmaxf(fmaxf(sv[4], sv[5]), sv[6]), sv[7]);
    float t2 = fmaxf(fmaxf(fmaxf(sv[8], sv[9]), sv[10]), sv[11]);
    float t3 = fmaxf(fmaxf(fmaxf(sv[12], sv[13]), sv[14]), sv[15]);
    float rmax = fmaxf(fmaxf(fmaxf(t0, t1), t2), t3);
    rmax = fmaxf(rmax, __shfl_xor(rmax, 16));
    rmax = fmaxf(rmax, __shfl_xor(rmax, 32));

    // defer-max (T13): rescale only if max grew past threshold (exp2 domain)
    if (!__all(rmax <= mi + 8.f)) {
      const float newm = fmaxf(mi, rmax);
      const float corr = exp2_fast(mi - newm);
      mi = newm;
      li *= corr;
      float cf[4];
#pragma unroll
      for (int j = 0; j < 4; ++j) cf[j] = __shfl(corr, kg * 4 + j);
#pragma unroll
      for (int n = 0; n < 4; ++n)
#pragma unroll
        for (int j = 0; j < 4; ++j) oacc[n][j] *= cf[j];
    }

    float rsum = 0.f;
#pragma unroll
    for (int i = 0; i < 16; ++i) {
      sv[i] = exp2_fast(sv[i] - mi);   // raw v_exp_f32 (2^x)
      rsum += sv[i];
    }
    rsum += __shfl_xor(rsum, 16);
    rsum += __shfl_xor(rsum, 32);
    li += rsum;

    // P -> per-wave LDS via v_cvt_pk_bf16_f32 (T12), swizzled b64 writes
#pragma unroll
    for (int m = 0; m < 4; ++m) {
      uint2 pv;
      pv.x = cvt_pk_bf16(sv[m * 4 + 0], sv[m * 4 + 1]);
      pv.y = cvt_pk_bf16(sv[m * 4 + 2], sv[m * 4 + 3]);
      *(uint2*)&pl[lrow * 64 + ((m * 2 + (kg >> 1)) ^ t7) * 8 + (kg & 1) * 4] = pv;
    }
    asm volatile("s_waitcnt lgkmcnt(0)" ::: "memory");
    __builtin_amdgcn_sched_barrier(0);

    // O += P @ V
    __builtin_amdgcn_s_setprio(1);
#pragma unroll
    for (int s2 = 0; s2 < 2; ++s2) {
      const bf16x8 pa = *(const bf16x8*)&pl[lrow * 64 + ((s2 * 4 + kg) ^ t7) * 8];
#pragma unroll
      for (int n = 0; n < 4; ++n) {
        const int r = n * 16 + lrow;
        const bf16x8 bv = *(const bf16x8*)
            &Vs[cur][r * 64 + ((s2 * 4 + kg) ^ t7) * 8];
        oacc[n] = __builtin_amdgcn_mfma_f32_16x16x32_bf16(pa, bv, oacc[n], 0, 0, 0);
      }
    }
    __builtin_amdgcn_s_setprio(0);

    __syncthreads();  // drain staged kt+1 (vmcnt) + all waves done with cur
  }

  // epilogue: normalize (li redistributed via shfl), bf16 store
#pragma unroll
  for (int j = 0; j < 4; ++j) {
    const float lj = __shfl(li, kg * 4 + j);
    const float inv = 1.f / lj;
    const int q = q0 + w * 16 + kg * 4 + j;
#pragma unroll
    for (int n = 0; n < 4; ++n)
      AO[(size_t)(b * 2048 + q) * 1024 + h * 64 + n * 16 + lrow] =
          f2bf(oacc[n][j] * inv);
  }
}

// ---------------------------------------------------------------------------
extern "C" void kernel_launch(void* const* d_in, const int* in_sizes, int n_in,
                              void* d_out, int out_size, void* d_ws,
                              size_t ws_size, hipStream_t stream) {
  const float* x = (const float*)d_in[0];
  const int* mask = (const int*)d_in[1];
  const float* qkv_w = (const float*)d_in[2];
  const float* qkv_b = (const float*)d_in[3];
  const float* out_w = (const float*)d_in[4];
  const float* out_b = (const float*)d_in[5];
  float* out = (float*)d_out;

  ushort* p = (ushort*)d_ws;
  ushort* xb = p;      p += 4194304;   // x bf16 [4096][1024]
  ushort* qkvwb = p;   p += 3145728;   // qkv_w bf16 [3072][1024]
  ushort* outwb = p;   p += 1048576;   // out_w bf16 [1024][1024]
  ushort* q_ws = p;    p += 4194304;   // [32][2048][64] (pre-scaled, exp2 dom.)
  ushort* k_ws = p;    p += 4194304;   // [32][2048][64]
  ushort* vt_ws = p;   p += 4194304;   // [32][64][2048] (transposed in GEMM)
  ushort* ao_ws = p;   p += 4194304;   // [4096][1024] bf16
  int* flags = (int*)p;                // [2][32][32]

  cvt_f32_bf16<<<2048, 256, 0, stream>>>(x, xb, 524288);
  cvt_f32_bf16<<<1536, 256, 0, stream>>>(qkv_w, qkvwb, 393216);
  cvt_f32_bf16<<<512, 256, 0, stream>>>(out_w, outwb, 131072);
  mask_flags<<<2048, 256, 0, stream>>>(mask, flags);
  gemm_bt<1><<<dim3(32, 24), 256, 0, stream>>>(xb, qkvwb, qkv_b, q_ws, k_ws,
                                               vt_ws, nullptr);
  flash_attn<<<1024, 256, 0, stream>>>(q_ws, k_ws, vt_ws, mask, flags, ao_ws);
  gemm_bt<0><<<dim3(32, 8), 256, 0, stream>>>(ao_ws, outwb, out_b, nullptr,
                                              nullptr, nullptr, out);
}